// Round 11
// baseline (300.186 us; speedup 1.0000x reference)
//
#include <hip/hip_runtime.h>
#include <hip/hip_bf16.h>
#include <stdint.h>

#define B_ 2
#define C_ 512
#define G_ 4
#define D_ 128
#define N_ 4096

typedef __bf16 bf16;
typedef __bf16 bf16x8 __attribute__((ext_vector_type(8)));
typedef float  f32x4  __attribute__((ext_vector_type(4)));
typedef float  f32x16 __attribute__((ext_vector_type(16)));

#define MFMA   __builtin_amdgcn_mfma_f32_16x16x32_bf16
#define MFMA32 __builtin_amdgcn_mfma_f32_32x32x16_bf16

// LDS chunk swizzle for GEMMs: physical chunk = logical chunk ^ ((row>>1)&3)
#define SWZ(row, c) ((((c) ^ (((row) >> 1) & 3)) << 4))

// ---- workspace layout (bytes) ----
#define OFF_Q   (0u)           // [B*G][N][D] bf16 (pre-scaled by SC*log2e)
#define OFF_K   (8388608u)     // [B*G][N][D] bf16
#define OFF_VT  (16777216u)    // [B*G][D][N] bf16
#define OFF_XT  (25165824u)    // [B*N][C] bf16 (xT input; later attn O)
#define OFF_WB  (33554432u)    // 4 x [512][512] bf16
#define OFF_OP  (35651584u)    // bf16 [2][8][4096][128] partial O
#define OFF_ML  (52428800u)    // float2 [2][8][4096] running (m,l)
#define WS_NEED_SPLIT (52953088u)

__device__ inline unsigned pk2(float a, float b) {
    union { bf16 h[2]; unsigned u; } t;
    t.h[0] = (bf16)a; t.h[1] = (bf16)b;
    return t.u;
}
__device__ inline void pl32(unsigned &a, unsigned &b) {
    asm volatile("v_permlane32_swap_b32 %0, %1" : "+v"(a), "+v"(b));
}
__device__ inline void gload16(const char* src, char* lds) {
    __builtin_amdgcn_global_load_lds(
        (const __attribute__((address_space(1))) unsigned*)src,
        (__attribute__((address_space(3))) unsigned*)lds, 16, 0, 0);
}
__device__ inline float max3f(float a, float b, float c) {
    return fmaxf(fmaxf(a, b), c);   // clang fuses to v_max3_f32
}

// ---------- kernel 1: weights fp32 -> bf16 ----------
__global__ __launch_bounds__(256) void wcvt_kernel(const float* __restrict__ Wq,
                                                   const float* __restrict__ Wk,
                                                   const float* __restrict__ Wv,
                                                   const float* __restrict__ Wo,
                                                   bf16* __restrict__ out) {
    int m = blockIdx.y;
    const float* W = (m == 0) ? Wq : (m == 1) ? Wk : (m == 2) ? Wv : Wo;
    int i = (blockIdx.x * 256 + threadIdx.x) * 4;
    float4 v = *(const float4*)(W + i);
    union { bf16 h[4]; uint2 u; } pk;
    pk.h[0] = (bf16)v.x; pk.h[1] = (bf16)v.y; pk.h[2] = (bf16)v.z; pk.h[3] = (bf16)v.w;
    *(uint2*)(out + (size_t)m * (C_ * C_) + i) = pk.u;
}

// ---------- kernel 2: x [b][c][n] f32 -> xT [b*n][c] bf16 ----------
__global__ __launch_bounds__(256) void xt_kernel(const float* __restrict__ x,
                                                 bf16* __restrict__ xT) {
    __shared__ bf16 t[64 * 80];
    int n0 = blockIdx.x * 64, c0 = blockIdx.y * 64, b = blockIdx.z;
    const float* xp = x + (size_t)b * C_ * N_;
#pragma unroll
    for (int i = 0; i < 16; ++i) {
        int idx = threadIdx.x + 256 * i;
        int cl = idx >> 6, nl = idx & 63;
        float v = xp[(size_t)(c0 + cl) * N_ + n0 + nl];
        t[nl * 80 + cl] = (bf16)v;
    }
    __syncthreads();
    bf16* xt = xT + ((size_t)b * N_ + n0) * C_ + c0;
#pragma unroll
    for (int i = 0; i < 2; ++i) {
        int id = threadIdx.x + 256 * i;
        int nl = id >> 3, c8 = (id & 7) * 8;
        *(uint4*)(xt + (size_t)nl * C_ + c8) = *(const uint4*)(t + nl * 80 + c8);
    }
}

// ---------- kernel 3: fused QKV projection, 128x128 tile ----------
__global__ __launch_bounds__(256) void qkv_kernel(const bf16* __restrict__ xT,
                                                  const bf16* __restrict__ WB,
                                                  const float* __restrict__ bq,
                                                  const float* __restrict__ bk,
                                                  const float* __restrict__ bv,
                                                  bf16* __restrict__ Q,
                                                  bf16* __restrict__ K,
                                                  bf16* __restrict__ Vt) {
    __shared__ char smem[32768];
    const int tid = threadIdx.x;
    const int w = tid >> 6, l = tid & 63;
    const int lr = l & 15, lg = l >> 4;
    const int wr = w >> 1, wc = w & 1;
    const int mat = blockIdx.z;
    const bf16* A = xT;
    const bf16* W = WB + (size_t)mat * (C_ * C_);
    const float* bias = (mat == 0) ? bq : (mat == 1) ? bk : bv;
    const int r0 = blockIdx.x * 128, o0 = blockIdx.y * 128;
    const float QSCALE = 0.08838834764831845f * 1.4426950408889634f;

    const char* srcA[2]; const char* srcB[2]; int dA[2], dB[2];
#pragma unroll
    for (int i = 0; i < 2; ++i) {
        int CL = tid + 256 * i, row = CL >> 2, c = CL & 3;
        srcA[i] = (const char*)(A + (size_t)(r0 + row) * C_) + SWZ(row, c);
        srcB[i] = (const char*)(W + (size_t)(o0 + row) * C_) + SWZ(row, c);
        dA[i] = CL << 4;
        dB[i] = 8192 + (CL << 4);
    }

    f32x4 z = {0.f, 0.f, 0.f, 0.f};
    f32x4 acc[4][4];
#pragma unroll
    for (int m = 0; m < 4; ++m)
#pragma unroll
        for (int n = 0; n < 4; ++n) acc[m][n] = z;

    auto STAGE = [&](int buf, int kt) {
        char* base = smem + buf * 16384;
        int kb = kt * 64;
#pragma unroll
        for (int i = 0; i < 2; ++i) {
            gload16(srcA[i] + kb, base + dA[i]);
            gload16(srcB[i] + kb, base + dB[i]);
        }
    };

    STAGE(0, 0);
    __syncthreads();
#pragma unroll 4
    for (int t = 0; t < 16; ++t) {
        int cur = t & 1;
        if (t < 15) STAGE(cur ^ 1, t + 1);
        char* Ab = smem + cur * 16384;
        char* Bb = Ab + 8192;
        bf16x8 af[4], bg_[4];
#pragma unroll
        for (int m = 0; m < 4; ++m) {
            int row = wr * 64 + m * 16 + lr;
            af[m] = *(const bf16x8*)(Ab + row * 64 + SWZ(row, lg));
        }
#pragma unroll
        for (int n = 0; n < 4; ++n) {
            int row = wc * 64 + n * 16 + lr;
            bg_[n] = *(const bf16x8*)(Bb + row * 64 + SWZ(row, lg));
        }
#pragma unroll
        for (int m = 0; m < 4; ++m)
#pragma unroll
            for (int n = 0; n < 4; ++n)
                acc[m][n] = MFMA(af[m], bg_[n], acc[m][n], 0, 0, 0);
        __syncthreads();
    }

#pragma unroll
    for (int n = 0; n < 4; ++n) {
        int o = o0 + wc * 64 + n * 16 + lr;
        float bs = bias[o];
        int g = o >> 7, d = o & 127;
#pragma unroll
        for (int m = 0; m < 4; ++m) {
            int row = r0 + wr * 64 + m * 16 + lg * 4;
            int b = row >> 12, nn = row & (N_ - 1);
            if (mat == 0) {
#pragma unroll
                for (int j = 0; j < 4; ++j)
                    Q[((size_t)(b * G_ + g) * N_ + nn + j) * D_ + d] =
                        (bf16)((acc[m][n][j] + bs) * QSCALE);
            } else if (mat == 1) {
#pragma unroll
                for (int j = 0; j < 4; ++j)
                    K[((size_t)(b * G_ + g) * N_ + nn + j) * D_ + d] =
                        (bf16)(acc[m][n][j] + bs);
            } else {
                union { bf16 h[4]; uint2 u; } pk;
#pragma unroll
                for (int j = 0; j < 4; ++j) pk.h[j] = (bf16)(acc[m][n][j] + bs);
                *(uint2*)(Vt + ((size_t)(b * G_ + g) * D_ + d) * N_ + nn) = pk.u;
            }
        }
    }
}

// ---------- kernel 4: flash attention, 32x32 swapped-QK, KVB=64, 8-wave blocks ----------
// 8 waves x 32 q = 256 q/block; LDS 64KB (dbuf K+V) shared by 8 waves
// -> 2 blocks/CU = 16 waves/CU = 4 waves/SIMD. head = L&7 (XCD-locality preserved).
template<int SPLITS>
__global__ __launch_bounds__(512, 4) void attn_kernel(const bf16* __restrict__ Q,
                                                      const bf16* __restrict__ K,
                                                      const bf16* __restrict__ Vt,
                                                      bf16* __restrict__ XT,
                                                      bf16* __restrict__ Op,
                                                      float* __restrict__ ML) {
    __shared__ char smem[65536];
    const int tid = threadIdx.x;
    const int w = tid >> 6, l = tid & 63;
    const int l31 = l & 31, h = l >> 5;

    // 1-D grid: 256 (SPLITS=2) or 128 (SPLITS=1); xcd = L%8 -> head
    const int L = blockIdx.x;
    const int bg = L & 7;
    const int ix = L >> 3;
    const int sp = (SPLITS > 1) ? (ix >> 4) : 0;
    const int qb = (SPLITS > 1) ? (ix & 15) : ix;

    const bf16* Qh = Q + (size_t)bg * N_ * D_;
    const char* Kh = (const char*)(K + (size_t)bg * N_ * D_);
    const char* Vh = (const char*)(Vt + (size_t)bg * D_ * N_);
    const int q0 = qb * 256 + w * 32;
    const int kv0 = sp * (N_ / SPLITS);
    const int NT = N_ / SPLITS / 64;

    // staging offsets: 8 waves x 2 chunks each for K (1024 chunks) and V
    int offK[2], offV[2];
#pragma unroll
    for (int j = 0; j < 2; ++j) {
        int CL = (w * 2 + j) * 64 + l;
        int row = CL >> 4;
        int cp = (CL & 15) ^ (row & 15);
        offK[j] = row * 256 + cp * 16;
        int dv = 2 * row + (cp >> 3), k8 = cp & 7;
        offV[j] = dv * (N_ * 2) + k8 * 16;
    }

    bf16x8 aq[8];
#pragma unroll
    for (int kb = 0; kb < 8; ++kb)
        aq[kb] = *(const bf16x8*)(Qh + (size_t)(q0 + l31) * D_ + kb * 16 + h * 8);

    bf16 one_ = (bf16)1.0f;
    bf16x8 ones = {one_, one_, one_, one_, one_, one_, one_, one_};

    f32x16 oacc[4], lacc;
#pragma unroll
    for (int dt = 0; dt < 4; ++dt)
#pragma unroll
        for (int r = 0; r < 16; ++r) oacc[dt][r] = 0.f;
#pragma unroll
    for (int r = 0; r < 16; ++r) lacc[r] = 0.f;
    float mrun = -1e30f;
    const float THR = 5.0f;

    auto STAGE = [&](int buf, int kv) {
        const char* pk = Kh + (size_t)kv * 256;
        const char* pv = Vh + (size_t)kv * 2;
        char* kb = smem + buf * 32768 + w * 2048;
        char* vb = smem + buf * 32768 + 16384 + w * 2048;
#pragma unroll
        for (int j = 0; j < 2; ++j) gload16(pk + offK[j], kb + j * 1024);
#pragma unroll
        for (int j = 0; j < 2; ++j) gload16(pv + offV[j], vb + j * 1024);
    };

    STAGE(0, kv0);

    for (int t = 0; t < NT; ++t) {
        int cur = t & 1;
        __builtin_amdgcn_s_barrier();
        if (t + 1 < NT) {
            STAGE(cur ^ 1, kv0 + (t + 1) * 64);
            asm volatile("s_waitcnt vmcnt(4)" ::: "memory");  // drain tile t, keep t+1 in flight
        } else {
            asm volatile("s_waitcnt vmcnt(0)" ::: "memory");
        }
        __builtin_amdgcn_sched_barrier(0);
        __builtin_amdgcn_s_barrier();
        char* Kb = smem + cur * 32768;
        char* Vb = smem + cur * 32768 + 16384;

        // ---- S^T = K Q^T ----
        f32x16 s0, s1;
#pragma unroll
        for (int r = 0; r < 16; ++r) { s0[r] = 0.f; s1[r] = 0.f; }
        __builtin_amdgcn_s_setprio(1);
#pragma unroll
        for (int kb = 0; kb < 8; ++kb) {
            int ch = (((kb << 1) | h) ^ (l31 & 15)) << 4;
            bf16x8 kf0 = *(const bf16x8*)(Kb + (size_t)l31 * 256 + ch);
            s0 = MFMA32(kf0, aq[kb], s0, 0, 0, 0);
            bf16x8 kf1 = *(const bf16x8*)(Kb + (size_t)(32 + l31) * 256 + ch);
            s1 = MFMA32(kf1, aq[kb], s1, 0, 0, 0);
        }
        __builtin_amdgcn_s_setprio(0);

        // ---- tile max via max3 tree (lane owns q = l31) ----
        float x0 = max3f(s0[0],  s0[1],  s0[2]);
        float x1 = max3f(s0[3],  s0[4],  s0[5]);
        float x2 = max3f(s0[6],  s0[7],  s0[8]);
        float x3 = max3f(s0[9],  s0[10], s0[11]);
        float x4 = max3f(s0[12], s0[13], s0[14]);
        float x5 = max3f(s0[15], s1[0],  s1[1]);
        float x6 = max3f(s1[2],  s1[3],  s1[4]);
        float x7 = max3f(s1[5],  s1[6],  s1[7]);
        float x8 = max3f(s1[8],  s1[9],  s1[10]);
        float x9 = max3f(s1[11], s1[12], s1[13]);
        float xa = fmaxf(s1[14], s1[15]);
        float y0 = max3f(x0, x1, x2);
        float y1 = max3f(x3, x4, x5);
        float y2 = max3f(x6, x7, x8);
        float y3 = fmaxf(x9, xa);
        float mt = fmaxf(max3f(y0, y1, y2), y3);
        mt = fmaxf(mt, __shfl_xor(mt, 32));

        if (__any(mt > mrun + THR)) {
            float mn = fmaxf(mrun, mt);
            float corr = __builtin_amdgcn_exp2f(mrun - mn);
            mrun = mn;
#pragma unroll
            for (int r = 0; r < 16; ++r) {
                int qr = (r & 3) + 8 * (r >> 2) + 4 * h;
                float cr = __shfl(corr, qr);
                lacc[r] *= cr;
#pragma unroll
                for (int dt = 0; dt < 4; ++dt) oacc[dt][r] *= cr;
            }
        }

#pragma unroll
        for (int r = 0; r < 16; ++r) {
            s0[r] = __builtin_amdgcn_exp2f(s0[r] - mrun);
            s1[r] = __builtin_amdgcn_exp2f(s1[r] - mrun);
        }

        // ---- P -> bf16 PV A-fragments via pack + permlane32_swap ----
        bf16x8 pa0, pa1, pa2, pa3;
        {
            unsigned x0_ = pk2(s0[0], s0[1]),  y0_ = pk2(s0[4], s0[5]);  pl32(x0_, y0_);
            unsigned x1_ = pk2(s0[2], s0[3]),  y1_ = pk2(s0[6], s0[7]);  pl32(x1_, y1_);
            pa0 = __builtin_bit_cast(bf16x8, (uint4){x0_, x1_, y0_, y1_});
            unsigned x2_ = pk2(s0[8], s0[9]),  y2_ = pk2(s0[12], s0[13]); pl32(x2_, y2_);
            unsigned x3_ = pk2(s0[10], s0[11]), y3_ = pk2(s0[14], s0[15]); pl32(x3_, y3_);
            pa1 = __builtin_bit_cast(bf16x8, (uint4){x2_, x3_, y2_, y3_});
            unsigned x4_ = pk2(s1[0], s1[1]),  y4_ = pk2(s1[4], s1[5]);  pl32(x4_, y4_);
            unsigned x5_ = pk2(s1[2], s1[3]),  y5_ = pk2(s1[6], s1[7]);  pl32(x5_, y5_);
            pa2 = __builtin_bit_cast(bf16x8, (uint4){x4_, x5_, y4_, y5_});
            unsigned x6_ = pk2(s1[8], s1[9]),  y6_ = pk2(s1[12], s1[13]); pl32(x6_, y6_);
            unsigned x7_ = pk2(s1[10], s1[11]), y7_ = pk2(s1[14], s1[15]); pl32(x7_, y7_);
            pa3 = __builtin_bit_cast(bf16x8, (uint4){x6_, x7_, y6_, y7_});
        }

        // ---- O += P V ; l += P 1 (row-sum on the MFMA pipe) ----
        __builtin_amdgcn_s_setprio(1);
#pragma unroll
        for (int sl = 0; sl < 4; ++sl) {
            bf16x8 pa = (sl == 0) ? pa0 : (sl == 1) ? pa1 : (sl == 2) ? pa2 : pa3;
#pragma unroll
            for (int dt = 0; dt < 4; ++dt) {
                int row = dt * 16 + (l31 >> 1);
                int ch = ((((l31 & 1) << 3) + (sl << 1) + h) ^ (l31 >> 1)) << 4;
                bf16x8 vf = *(const bf16x8*)(Vb + (size_t)row * 256 + ch);
                oacc[dt] = MFMA32(pa, vf, oacc[dt], 0, 0, 0);
            }
            lacc = MFMA32(pa, ones, lacc, 0, 0, 0);
        }
        __builtin_amdgcn_s_setprio(0);
    }

    // ---- epilogue ----
    if (SPLITS > 1) {
        float2* mlp = (float2*)ML + ((size_t)sp * 8 + bg) * N_ + q0;
#pragma unroll
        for (int r = 0; r < 16; ++r) {
            int qr = (r & 3) + 8 * (r >> 2) + 4 * h;
            float mv = __shfl(mrun, qr);
            if (l31 == 0) {
                float2 v; v.x = mv; v.y = lacc[r];
                mlp[qr] = v;
            }
        }
        bf16* op = Op + (((size_t)sp * 8 + bg) * N_ + q0) * D_;
#pragma unroll
        for (int dt = 0; dt < 4; ++dt)
#pragma unroll
            for (int r = 0; r < 16; ++r) {
                int qr = (r & 3) + 8 * (r >> 2) + 4 * h;
                op[(size_t)qr * D_ + dt * 32 + l31] = (bf16)oacc[dt][r];
            }
    } else {
        int b = bg >> 2, g = bg & 3;
#pragma unroll
        for (int r = 0; r < 16; ++r) {
            int qr = (r & 3) + 8 * (r >> 2) + 4 * h;
            float iv = 1.f / lacc[r];
#pragma unroll
            for (int dt = 0; dt < 4; ++dt)
                XT[((size_t)b * N_ + q0 + qr) * C_ + g * D_ + dt * 32 + l31] =
                    (bf16)(oacc[dt][r] * iv);
        }
    }
}

// ---------- kernel 4b: merge the 2 KV-split partials ----------
__global__ __launch_bounds__(256) void merge_kernel(const bf16* __restrict__ Op,
                                                    const float* __restrict__ ML,
                                                    bf16* __restrict__ XT) {
    int t = threadIdx.x & 15, rl = threadIdx.x >> 4;
    int r = blockIdx.x * 16 + rl;
    int bg = r >> 12, n = r & (N_ - 1);
    const float2* mlp = (const float2*)ML;
    float2 ml0 = mlp[r], ml1 = mlp[32768 + r];
    float mm = fmaxf(ml0.x, ml1.x);
    float w0 = __builtin_amdgcn_exp2f(ml0.x - mm);
    float w1 = __builtin_amdgcn_exp2f(ml1.x - mm);
    float inv = 1.f / (w0 * ml0.y + w1 * ml1.y);
    w0 *= inv; w1 *= inv;
    bf16x8 o0 = *(const bf16x8*)(Op + (size_t)r * D_ + t * 8);
    bf16x8 o1 = *(const bf16x8*)(Op + (size_t)(32768 + r) * D_ + t * 8);
    union { bf16 h[8]; uint4 u; } pk;
#pragma unroll
    for (int e = 0; e < 8; ++e)
        pk.h[e] = (bf16)(w0 * (float)o0[e] + w1 * (float)o1[e]);
    int b = bg >> 2, g = bg & 3;
    *(uint4*)(XT + ((size_t)b * N_ + n) * C_ + g * D_ + t * 8) = pk.u;
}

// ---------- kernel 5: output projection, 128x64 tile ----------
__global__ __launch_bounds__(256) void oproj_kernel(const bf16* __restrict__ Ob,
                                                    const bf16* __restrict__ WB,
                                                    const float* __restrict__ bo,
                                                    const float* __restrict__ x,
                                                    float* __restrict__ out) {
    __shared__ char smem[24576];
    const int tid = threadIdx.x;
    const int w = tid >> 6, l = tid & 63;
    const int lr = l & 15, lg = l >> 4;
    const int wr = w >> 1, wc = w & 1;
    const bf16* W = WB + (size_t)3 * (C_ * C_);
    const int r0 = blockIdx.x * 128, o0 = blockIdx.y * 64;

    const char* srcA[2]; int dA[2];
#pragma unroll
    for (int i = 0; i < 2; ++i) {
        int CL = tid + 256 * i, row = CL >> 2, c = CL & 3;
        srcA[i] = (const char*)(Ob + (size_t)(r0 + row) * C_) + SWZ(row, c);
        dA[i] = CL << 4;
    }
    const char* srcB; int dB;
    {
        int CL = tid, row = CL >> 2, c = CL & 3;
        srcB = (const char*)(W + (size_t)(o0 + row) * C_) + SWZ(row, c);
        dB = 8192 + (CL << 4);
    }

    f32x4 z = {0.f, 0.f, 0.f, 0.f};
    f32x4 acc[4][2];
#pragma unroll
    for (int m = 0; m < 4; ++m) { acc[m][0] = z; acc[m][1] = z; }

    auto STAGE = [&](int buf, int kt) {
        char* base = smem + buf * 12288;
        int kb = kt * 64;
#pragma unroll
        for (int i = 0; i < 2; ++i) gload16(srcA[i] + kb, base + dA[i]);
        gload16(srcB + kb, base + dB);
    };

    STAGE(0, 0);
    __syncthreads();
#pragma unroll 4
    for (int t = 0; t < 16; ++t) {
        int cur = t & 1;
        if (t < 15) STAGE(cur ^ 1, t + 1);
        char* Ab = smem + cur * 12288;
        char* Bb = Ab + 8192;
        bf16x8 af[4], bg_[2];
#pragma unroll
        for (int m = 0; m < 4; ++m) {
            int row = wr * 64 + m * 16 + lr;
            af[m] = *(const bf16x8*)(Ab + row * 64 + SWZ(row, lg));
        }
#pragma unroll
        for (int n = 0; n < 2; ++n) {
            int row = wc * 32 + n * 16 + lr;
            bg_[n] = *(const bf16x8*)(Bb + row * 64 + SWZ(row, lg));
        }
#pragma unroll
        for (int m = 0; m < 4; ++m)
#pragma unroll
            for (int n = 0; n < 2; ++n)
                acc[m][n] = MFMA(af[m], bg_[n], acc[m][n], 0, 0, 0);
        __syncthreads();
    }

#pragma unroll
    for (int n = 0; n < 2; ++n) {
        int o = o0 + wc * 32 + n * 16 + lr;
        float bs = bo[o];
#pragma unroll
        for (int m = 0; m < 4; ++m) {
            int row = r0 + wr * 64 + m * 16 + lg * 4;
            int b = row >> 12, nn = row & (N_ - 1);
            size_t base = ((size_t)b * C_ + o) * N_ + nn;
            float4 xv = *(const float4*)(x + base);
            float4 ov;
            ov.x = acc[m][n][0] + bs + xv.x;
            ov.y = acc[m][n][1] + bs + xv.y;
            ov.z = acc[m][n][2] + bs + xv.z;
            ov.w = acc[m][n][3] + bs + xv.w;
            *(float4*)(out + base) = ov;
        }
    }
}

extern "C" void kernel_launch(void* const* d_in, const int* in_sizes, int n_in,
                              void* d_out, int out_size, void* d_ws, size_t ws_size,
                              hipStream_t stream) {
    const float* x  = (const float*)d_in[0];
    const float* Wq = (const float*)d_in[1];
    const float* bq = (const float*)d_in[2];
    const float* Wk = (const float*)d_in[3];
    const float* bk = (const float*)d_in[4];
    const float* Wv = (const float*)d_in[5];
    const float* bv = (const float*)d_in[6];
    const float* Wo = (const float*)d_in[7];
    const float* bo = (const float*)d_in[8];

    char* ws = (char*)d_ws;
    bf16* Q   = (bf16*)(ws + OFF_Q);
    bf16* K   = (bf16*)(ws + OFF_K);
    bf16* Vt  = (bf16*)(ws + OFF_VT);
    bf16* XT  = (bf16*)(ws + OFF_XT);
    bf16* WB  = (bf16*)(ws + OFF_WB);
    bf16* Op  = (bf16*)(ws + OFF_OP);
    float* ML = (float*)(ws + OFF_ML);
    float* out = (float*)d_out;

    hipLaunchKernelGGL(wcvt_kernel, dim3(256, 4), dim3(256), 0, stream, Wq, Wk, Wv, Wo, WB);
    hipLaunchKernelGGL(xt_kernel, dim3(64, 8, 2), dim3(256), 0, stream, x, XT);
    hipLaunchKernelGGL(qkv_kernel, dim3(64, 4, 3), dim3(256), 0, stream,
                       XT, WB, bq, bk, bv, Q, K, Vt);
    if (ws_size >= (size_t)WS_NEED_SPLIT) {
        hipLaunchKernelGGL(attn_kernel<2>, dim3(256), dim3(512), 0, stream,
                           Q, K, Vt, XT, Op, ML);
        hipLaunchKernelGGL(merge_kernel, dim3(2048), dim3(256), 0, stream, Op, ML, XT);
    } else {
        hipLaunchKernelGGL(attn_kernel<1>, dim3(128), dim3(512), 0, stream,
                           Q, K, Vt, XT, Op, ML);
    }
    hipLaunchKernelGGL(oproj_kernel, dim3(64, 8), dim3(256), 0, stream, XT, WB, bo, x, out);
}

// Round 12
// 137.719 us; speedup vs baseline: 2.1797x; 2.1797x over previous
//
#include <hip/hip_runtime.h>
#include <hip/hip_bf16.h>
#include <stdint.h>

#define B_ 2
#define C_ 512
#define G_ 4
#define D_ 128
#define N_ 4096

typedef __bf16 bf16;
typedef __bf16 bf16x8 __attribute__((ext_vector_type(8)));
typedef float  f32x4  __attribute__((ext_vector_type(4)));
typedef float  f32x16 __attribute__((ext_vector_type(16)));

#define MFMA   __builtin_amdgcn_mfma_f32_16x16x32_bf16
#define MFMA32 __builtin_amdgcn_mfma_f32_32x32x16_bf16

// LDS chunk swizzle for GEMMs: physical chunk = logical chunk ^ ((row>>1)&3)
#define SWZ(row, c) ((((c) ^ (((row) >> 1) & 3)) << 4))

// ---- workspace layout (bytes) ----
#define OFF_Q   (0u)           // [B*G][N][D] bf16 (pre-scaled by SC*log2e)
#define OFF_K   (8388608u)     // [B*G][N][D] bf16
#define OFF_VT  (16777216u)    // [B*G][D][N] bf16
#define OFF_XT  (25165824u)    // [B*N][C] bf16 (xT input; later attn O)
#define OFF_WB  (33554432u)    // 4 x [512][512] bf16
#define OFF_OP  (35651584u)    // bf16 [2][8][4096][128] partial O
#define OFF_ML  (52428800u)    // float2 [2][8][4096] running (m,l)
#define WS_NEED_SPLIT (52953088u)

__device__ inline unsigned pk2(float a, float b) {
    union { bf16 h[2]; unsigned u; } t;
    t.h[0] = (bf16)a; t.h[1] = (bf16)b;
    return t.u;
}
__device__ inline void pl32(unsigned &a, unsigned &b) {
    asm volatile("v_permlane32_swap_b32 %0, %1" : "+v"(a), "+v"(b));
}
__device__ inline void gload16(const char* src, char* lds) {
    __builtin_amdgcn_global_load_lds(
        (const __attribute__((address_space(1))) unsigned*)src,
        (__attribute__((address_space(3))) unsigned*)lds, 16, 0, 0);
}
__device__ inline float max3f(float a, float b, float c) {
    return fmaxf(fmaxf(a, b), c);   // clang fuses to v_max3_f32
}

// ---------- kernel 1: weights fp32 -> bf16 ----------
__global__ __launch_bounds__(256) void wcvt_kernel(const float* __restrict__ Wq,
                                                   const float* __restrict__ Wk,
                                                   const float* __restrict__ Wv,
                                                   const float* __restrict__ Wo,
                                                   bf16* __restrict__ out) {
    int m = blockIdx.y;
    const float* W = (m == 0) ? Wq : (m == 1) ? Wk : (m == 2) ? Wv : Wo;
    int i = (blockIdx.x * 256 + threadIdx.x) * 4;
    float4 v = *(const float4*)(W + i);
    union { bf16 h[4]; uint2 u; } pk;
    pk.h[0] = (bf16)v.x; pk.h[1] = (bf16)v.y; pk.h[2] = (bf16)v.z; pk.h[3] = (bf16)v.w;
    *(uint2*)(out + (size_t)m * (C_ * C_) + i) = pk.u;
}

// ---------- kernel 2: x [b][c][n] f32 -> xT [b*n][c] bf16 ----------
__global__ __launch_bounds__(256) void xt_kernel(const float* __restrict__ x,
                                                 bf16* __restrict__ xT) {
    __shared__ bf16 t[64 * 80];
    int n0 = blockIdx.x * 64, c0 = blockIdx.y * 64, b = blockIdx.z;
    const float* xp = x + (size_t)b * C_ * N_;
#pragma unroll
    for (int i = 0; i < 16; ++i) {
        int idx = threadIdx.x + 256 * i;
        int cl = idx >> 6, nl = idx & 63;
        float v = xp[(size_t)(c0 + cl) * N_ + n0 + nl];
        t[nl * 80 + cl] = (bf16)v;
    }
    __syncthreads();
    bf16* xt = xT + ((size_t)b * N_ + n0) * C_ + c0;
#pragma unroll
    for (int i = 0; i < 2; ++i) {
        int id = threadIdx.x + 256 * i;
        int nl = id >> 3, c8 = (id & 7) * 8;
        *(uint4*)(xt + (size_t)nl * C_ + c8) = *(const uint4*)(t + nl * 80 + c8);
    }
}

// ---------- kernel 3: fused QKV projection, 128x128 tile ----------
__global__ __launch_bounds__(256) void qkv_kernel(const bf16* __restrict__ xT,
                                                  const bf16* __restrict__ WB,
                                                  const float* __restrict__ bq,
                                                  const float* __restrict__ bk,
                                                  const float* __restrict__ bv,
                                                  bf16* __restrict__ Q,
                                                  bf16* __restrict__ K,
                                                  bf16* __restrict__ Vt) {
    __shared__ char smem[32768];
    const int tid = threadIdx.x;
    const int w = tid >> 6, l = tid & 63;
    const int lr = l & 15, lg = l >> 4;
    const int wr = w >> 1, wc = w & 1;
    const int mat = blockIdx.z;
    const bf16* A = xT;
    const bf16* W = WB + (size_t)mat * (C_ * C_);
    const float* bias = (mat == 0) ? bq : (mat == 1) ? bk : bv;
    const int r0 = blockIdx.x * 128, o0 = blockIdx.y * 128;
    const float QSCALE = 0.08838834764831845f * 1.4426950408889634f;

    const char* srcA[2]; const char* srcB[2]; int dA[2], dB[2];
#pragma unroll
    for (int i = 0; i < 2; ++i) {
        int CL = tid + 256 * i, row = CL >> 2, c = CL & 3;
        srcA[i] = (const char*)(A + (size_t)(r0 + row) * C_) + SWZ(row, c);
        srcB[i] = (const char*)(W + (size_t)(o0 + row) * C_) + SWZ(row, c);
        dA[i] = CL << 4;
        dB[i] = 8192 + (CL << 4);
    }

    f32x4 z = {0.f, 0.f, 0.f, 0.f};
    f32x4 acc[4][4];
#pragma unroll
    for (int m = 0; m < 4; ++m)
#pragma unroll
        for (int n = 0; n < 4; ++n) acc[m][n] = z;

    auto STAGE = [&](int buf, int kt) {
        char* base = smem + buf * 16384;
        int kb = kt * 64;
#pragma unroll
        for (int i = 0; i < 2; ++i) {
            gload16(srcA[i] + kb, base + dA[i]);
            gload16(srcB[i] + kb, base + dB[i]);
        }
    };

    STAGE(0, 0);
    __syncthreads();
#pragma unroll 4
    for (int t = 0; t < 16; ++t) {
        int cur = t & 1;
        if (t < 15) STAGE(cur ^ 1, t + 1);
        char* Ab = smem + cur * 16384;
        char* Bb = Ab + 8192;
        bf16x8 af[4], bg_[4];
#pragma unroll
        for (int m = 0; m < 4; ++m) {
            int row = wr * 64 + m * 16 + lr;
            af[m] = *(const bf16x8*)(Ab + row * 64 + SWZ(row, lg));
        }
#pragma unroll
        for (int n = 0; n < 4; ++n) {
            int row = wc * 64 + n * 16 + lr;
            bg_[n] = *(const bf16x8*)(Bb + row * 64 + SWZ(row, lg));
        }
#pragma unroll
        for (int m = 0; m < 4; ++m)
#pragma unroll
            for (int n = 0; n < 4; ++n)
                acc[m][n] = MFMA(af[m], bg_[n], acc[m][n], 0, 0, 0);
        __syncthreads();
    }

#pragma unroll
    for (int n = 0; n < 4; ++n) {
        int o = o0 + wc * 64 + n * 16 + lr;
        float bs = bias[o];
        int g = o >> 7, d = o & 127;
#pragma unroll
        for (int m = 0; m < 4; ++m) {
            int row = r0 + wr * 64 + m * 16 + lg * 4;
            int b = row >> 12, nn = row & (N_ - 1);
            if (mat == 0) {
#pragma unroll
                for (int j = 0; j < 4; ++j)
                    Q[((size_t)(b * G_ + g) * N_ + nn + j) * D_ + d] =
                        (bf16)((acc[m][n][j] + bs) * QSCALE);
            } else if (mat == 1) {
#pragma unroll
                for (int j = 0; j < 4; ++j)
                    K[((size_t)(b * G_ + g) * N_ + nn + j) * D_ + d] =
                        (bf16)(acc[m][n][j] + bs);
            } else {
                union { bf16 h[4]; uint2 u; } pk;
#pragma unroll
                for (int j = 0; j < 4; ++j) pk.h[j] = (bf16)(acc[m][n][j] + bs);
                *(uint2*)(Vt + ((size_t)(b * G_ + g) * D_ + d) * N_ + nn) = pk.u;
            }
        }
    }
}

// ---------- kernel 4: flash attention, 32x32 swapped-QK, KVB=64 ----------
// In-wave 1-tile software pipeline: S(t+1) MFMA issued BEFORE softmax(t) VALU,
// so every wave always has independent MFMA behind its VALU. Split K/V dbufs:
// K staged 2 tiles ahead, V 1 tile ahead; counted vmcnt drains {K(t+1),V(t)}.
template<int SPLITS>
__global__ __launch_bounds__(256, 2) void attn_kernel(const bf16* __restrict__ Q,
                                                      const bf16* __restrict__ K,
                                                      const bf16* __restrict__ Vt,
                                                      bf16* __restrict__ XT,
                                                      bf16* __restrict__ Op,
                                                      float* __restrict__ ML) {
    __shared__ char smem[65536];   // K0 @0, K1 @16K, V0 @32K, V1 @48K
    const int tid = threadIdx.x;
    const int w = tid >> 6, l = tid & 63;
    const int l31 = l & 31, h = l >> 5;

    // 1-D grid; xcd = L%8 -> head (L2 locality, round 10)
    const int L = blockIdx.x;
    const int bg = L & 7;
    const int ix = L >> 3;
    const int sp = (SPLITS > 1) ? (ix >> 5) : 0;
    const int qb = (SPLITS > 1) ? (ix & 31) : ix;

    const bf16* Qh = Q + (size_t)bg * N_ * D_;
    const char* Kh = (const char*)(K + (size_t)bg * N_ * D_);
    const char* Vh = (const char*)(Vt + (size_t)bg * D_ * N_);
    const int q0 = qb * 128 + w * 32;
    const int kv0 = sp * (N_ / SPLITS);
    const int NT = N_ / SPLITS / 64;

    int offK[4], offV[4];
#pragma unroll
    for (int j = 0; j < 4; ++j) {
        int CL = (w * 4 + j) * 64 + l;
        int row = CL >> 4;
        int cp = (CL & 15) ^ (row & 15);
        offK[j] = row * 256 + cp * 16;
        int dv = 2 * row + (cp >> 3), k8 = cp & 7;
        offV[j] = dv * (N_ * 2) + k8 * 16;
    }

    bf16x8 aq[8];
#pragma unroll
    for (int kb = 0; kb < 8; ++kb)
        aq[kb] = *(const bf16x8*)(Qh + (size_t)(q0 + l31) * D_ + kb * 16 + h * 8);

    bf16 one_ = (bf16)1.0f;
    bf16x8 ones = {one_, one_, one_, one_, one_, one_, one_, one_};

    f32x16 oacc[4], lacc;
#pragma unroll
    for (int dt = 0; dt < 4; ++dt)
#pragma unroll
        for (int r = 0; r < 16; ++r) oacc[dt][r] = 0.f;
#pragma unroll
    for (int r = 0; r < 16; ++r) lacc[r] = 0.f;
    float mrun = -1e30f;
    const float THR = 5.0f;

    auto STAGE_K = [&](int buf, int kv) {
        const char* pk = Kh + (size_t)kv * 256;
        char* kb = smem + buf * 16384 + w * 4096;
#pragma unroll
        for (int j = 0; j < 4; ++j) gload16(pk + offK[j], kb + j * 1024);
    };
    auto STAGE_V = [&](int buf, int kv) {
        const char* pv = Vh + (size_t)kv * 2;
        char* vb = smem + 32768 + buf * 16384 + w * 4096;
#pragma unroll
        for (int j = 0; j < 4; ++j) gload16(pv + offV[j], vb + j * 1024);
    };

    // prolog: K(0), V(0), K(1); drain K(0) only (leave V(0),K(1) in flight)
    STAGE_K(0, kv0);
    STAGE_V(0, kv0);
    if (NT > 1) STAGE_K(1, kv0 + 64);
    if (NT > 1) asm volatile("s_waitcnt vmcnt(8)" ::: "memory");
    else        asm volatile("s_waitcnt vmcnt(4)" ::: "memory");
    __builtin_amdgcn_sched_barrier(0);
    __builtin_amdgcn_s_barrier();

    // S(0) -> sP
    f32x16 sP0, sP1, sN0, sN1;
    {
        char* Kb = smem;
#pragma unroll
        for (int r = 0; r < 16; ++r) { sP0[r] = 0.f; sP1[r] = 0.f; }
        __builtin_amdgcn_s_setprio(1);
#pragma unroll
        for (int kb = 0; kb < 8; ++kb) {
            int ch = (((kb << 1) | h) ^ (l31 & 15)) << 4;
            bf16x8 kf0 = *(const bf16x8*)(Kb + (size_t)l31 * 256 + ch);
            sP0 = MFMA32(kf0, aq[kb], sP0, 0, 0, 0);
            bf16x8 kf1 = *(const bf16x8*)(Kb + (size_t)(32 + l31) * 256 + ch);
            sP1 = MFMA32(kf1, aq[kb], sP1, 0, 0, 0);
        }
        __builtin_amdgcn_s_setprio(0);
    }

#pragma unroll 2
    for (int t = 0; t < NT; ++t) {
        const int p = t & 1, q = p ^ 1;
        __builtin_amdgcn_s_barrier();                   // B1: prev-iter reads done
        if (t + 2 < NT) STAGE_K(p, kv0 + (t + 2) * 64); // overwrite K(t) slot
        if (t + 1 < NT) STAGE_V(q, kv0 + (t + 1) * 64); // overwrite V(t-1) slot
        if (t + 2 < NT)      asm volatile("s_waitcnt vmcnt(8)" ::: "memory");
        else if (t + 1 < NT) asm volatile("s_waitcnt vmcnt(4)" ::: "memory");
        else                 asm volatile("s_waitcnt vmcnt(0)" ::: "memory");
        __builtin_amdgcn_sched_barrier(0);
        __builtin_amdgcn_s_barrier();                   // B2: K(t+1),V(t) visible

        // ---- S(t+1) -> sN (independent MFMA ahead of softmax VALU) ----
        if (t + 1 < NT) {
            char* Kb = smem + q * 16384;
#pragma unroll
            for (int r = 0; r < 16; ++r) { sN0[r] = 0.f; sN1[r] = 0.f; }
            __builtin_amdgcn_s_setprio(1);
#pragma unroll
            for (int kb = 0; kb < 8; ++kb) {
                int ch = (((kb << 1) | h) ^ (l31 & 15)) << 4;
                bf16x8 kf0 = *(const bf16x8*)(Kb + (size_t)l31 * 256 + ch);
                sN0 = MFMA32(kf0, aq[kb], sN0, 0, 0, 0);
                bf16x8 kf1 = *(const bf16x8*)(Kb + (size_t)(32 + l31) * 256 + ch);
                sN1 = MFMA32(kf1, aq[kb], sN1, 0, 0, 0);
            }
            __builtin_amdgcn_s_setprio(0);
        }

        // ---- softmax(t) on sP (lane owns q = l31) ----
        float x0 = max3f(sP0[0],  sP0[1],  sP0[2]);
        float x1 = max3f(sP0[3],  sP0[4],  sP0[5]);
        float x2 = max3f(sP0[6],  sP0[7],  sP0[8]);
        float x3 = max3f(sP0[9],  sP0[10], sP0[11]);
        float x4 = max3f(sP0[12], sP0[13], sP0[14]);
        float x5 = max3f(sP0[15], sP1[0],  sP1[1]);
        float x6 = max3f(sP1[2],  sP1[3],  sP1[4]);
        float x7 = max3f(sP1[5],  sP1[6],  sP1[7]);
        float x8 = max3f(sP1[8],  sP1[9],  sP1[10]);
        float x9 = max3f(sP1[11], sP1[12], sP1[13]);
        float xa = fmaxf(sP1[14], sP1[15]);
        float y0 = max3f(x0, x1, x2);
        float y1 = max3f(x3, x4, x5);
        float y2 = max3f(x6, x7, x8);
        float y3 = fmaxf(x9, xa);
        float mt = fmaxf(max3f(y0, y1, y2), y3);
        mt = fmaxf(mt, __shfl_xor(mt, 32));

        if (__any(mt > mrun + THR)) {
            float mn = fmaxf(mrun, mt);
            float corr = __builtin_amdgcn_exp2f(mrun - mn);
            mrun = mn;
#pragma unroll
            for (int r = 0; r < 16; ++r) {
                int qr = (r & 3) + 8 * (r >> 2) + 4 * h;
                float cr = __shfl(corr, qr);
                lacc[r] *= cr;
#pragma unroll
                for (int dt = 0; dt < 4; ++dt) oacc[dt][r] *= cr;
            }
        }

#pragma unroll
        for (int r = 0; r < 16; ++r) {
            sP0[r] = __builtin_amdgcn_exp2f(sP0[r] - mrun);
            sP1[r] = __builtin_amdgcn_exp2f(sP1[r] - mrun);
        }

        // ---- P -> bf16 PV A-fragments via pack + permlane32_swap ----
        bf16x8 pa0, pa1, pa2, pa3;
        {
            unsigned x0_ = pk2(sP0[0], sP0[1]),  y0_ = pk2(sP0[4], sP0[5]);  pl32(x0_, y0_);
            unsigned x1_ = pk2(sP0[2], sP0[3]),  y1_ = pk2(sP0[6], sP0[7]);  pl32(x1_, y1_);
            pa0 = __builtin_bit_cast(bf16x8, (uint4){x0_, x1_, y0_, y1_});
            unsigned x2_ = pk2(sP0[8], sP0[9]),  y2_ = pk2(sP0[12], sP0[13]); pl32(x2_, y2_);
            unsigned x3_ = pk2(sP0[10], sP0[11]), y3_ = pk2(sP0[14], sP0[15]); pl32(x3_, y3_);
            pa1 = __builtin_bit_cast(bf16x8, (uint4){x2_, x3_, y2_, y3_});
            unsigned x4_ = pk2(sP1[0], sP1[1]),  y4_ = pk2(sP1[4], sP1[5]);  pl32(x4_, y4_);
            unsigned x5_ = pk2(sP1[2], sP1[3]),  y5_ = pk2(sP1[6], sP1[7]);  pl32(x5_, y5_);
            pa2 = __builtin_bit_cast(bf16x8, (uint4){x4_, x5_, y4_, y5_});
            unsigned x6_ = pk2(sP1[8], sP1[9]),  y6_ = pk2(sP1[12], sP1[13]); pl32(x6_, y6_);
            unsigned x7_ = pk2(sP1[10], sP1[11]), y7_ = pk2(sP1[14], sP1[15]); pl32(x7_, y7_);
            pa3 = __builtin_bit_cast(bf16x8, (uint4){x6_, x7_, y6_, y7_});
        }

        // ---- O += P V ; l += P 1 (reads Vbuf[p]) ----
        char* Vb = smem + 32768 + p * 16384;
        __builtin_amdgcn_s_setprio(1);
#pragma unroll
        for (int sl = 0; sl < 4; ++sl) {
            bf16x8 pa = (sl == 0) ? pa0 : (sl == 1) ? pa1 : (sl == 2) ? pa2 : pa3;
#pragma unroll
            for (int dt = 0; dt < 4; ++dt) {
                int row = dt * 16 + (l31 >> 1);
                int ch = ((((l31 & 1) << 3) + (sl << 1) + h) ^ (l31 >> 1)) << 4;
                bf16x8 vf = *(const bf16x8*)(Vb + (size_t)row * 256 + ch);
                oacc[dt] = MFMA32(pa, vf, oacc[dt], 0, 0, 0);
            }
            lacc = MFMA32(pa, ones, lacc, 0, 0, 0);
        }
        __builtin_amdgcn_s_setprio(0);

        sP0 = sN0; sP1 = sN1;   // pipeline rotate (unroll-2 renames away)
    }

    // ---- epilogue ----
    if (SPLITS > 1) {
        float2* mlp = (float2*)ML + ((size_t)sp * 8 + bg) * N_ + q0;
#pragma unroll
        for (int r = 0; r < 16; ++r) {
            int qr = (r & 3) + 8 * (r >> 2) + 4 * h;
            float mv = __shfl(mrun, qr);
            if (l31 == 0) {
                float2 v; v.x = mv; v.y = lacc[r];
                mlp[qr] = v;
            }
        }
        bf16* op = Op + (((size_t)sp * 8 + bg) * N_ + q0) * D_;
#pragma unroll
        for (int dt = 0; dt < 4; ++dt)
#pragma unroll
            for (int r = 0; r < 16; ++r) {
                int qr = (r & 3) + 8 * (r >> 2) + 4 * h;
                op[(size_t)qr * D_ + dt * 32 + l31] = (bf16)oacc[dt][r];
            }
    } else {
        int b = bg >> 2, g = bg & 3;
#pragma unroll
        for (int r = 0; r < 16; ++r) {
            int qr = (r & 3) + 8 * (r >> 2) + 4 * h;
            float iv = 1.f / lacc[r];
#pragma unroll
            for (int dt = 0; dt < 4; ++dt)
                XT[((size_t)b * N_ + q0 + qr) * C_ + g * D_ + dt * 32 + l31] =
                    (bf16)(oacc[dt][r] * iv);
        }
    }
}

// ---------- kernel 4b: merge the 2 KV-split partials ----------
__global__ __launch_bounds__(256) void merge_kernel(const bf16* __restrict__ Op,
                                                    const float* __restrict__ ML,
                                                    bf16* __restrict__ XT) {
    int t = threadIdx.x & 15, rl = threadIdx.x >> 4;
    int r = blockIdx.x * 16 + rl;
    int bg = r >> 12, n = r & (N_ - 1);
    const float2* mlp = (const float2*)ML;
    float2 ml0 = mlp[r], ml1 = mlp[32768 + r];
    float mm = fmaxf(ml0.x, ml1.x);
    float w0 = __builtin_amdgcn_exp2f(ml0.x - mm);
    float w1 = __builtin_amdgcn_exp2f(ml1.x - mm);
    float inv = 1.f / (w0 * ml0.y + w1 * ml1.y);
    w0 *= inv; w1 *= inv;
    bf16x8 o0 = *(const bf16x8*)(Op + (size_t)r * D_ + t * 8);
    bf16x8 o1 = *(const bf16x8*)(Op + (size_t)(32768 + r) * D_ + t * 8);
    union { bf16 h[8]; uint4 u; } pk;
#pragma unroll
    for (int e = 0; e < 8; ++e)
        pk.h[e] = (bf16)(w0 * (float)o0[e] + w1 * (float)o1[e]);
    int b = bg >> 2, g = bg & 3;
    *(uint4*)(XT + ((size_t)b * N_ + n) * C_ + g * D_ + t * 8) = pk.u;
}

// ---------- kernel 5: output projection, 128x64 tile ----------
__global__ __launch_bounds__(256) void oproj_kernel(const bf16* __restrict__ Ob,
                                                    const bf16* __restrict__ WB,
                                                    const float* __restrict__ bo,
                                                    const float* __restrict__ x,
                                                    float* __restrict__ out) {
    __shared__ char smem[24576];
    const int tid = threadIdx.x;
    const int w = tid >> 6, l = tid & 63;
    const int lr = l & 15, lg = l >> 4;
    const int wr = w >> 1, wc = w & 1;
    const bf16* W = WB + (size_t)3 * (C_ * C_);
    const int r0 = blockIdx.x * 128, o0 = blockIdx.y * 64;

    const char* srcA[2]; int dA[2];
#pragma unroll
    for (int i = 0; i < 2; ++i) {
        int CL = tid + 256 * i, row = CL >> 2, c = CL & 3;
        srcA[i] = (const char*)(Ob + (size_t)(r0 + row) * C_) + SWZ(row, c);
        dA[i] = CL << 4;
    }
    const char* srcB; int dB;
    {
        int CL = tid, row = CL >> 2, c = CL & 3;
        srcB = (const char*)(W + (size_t)(o0 + row) * C_) + SWZ(row, c);
        dB = 8192 + (CL << 4);
    }

    f32x4 z = {0.f, 0.f, 0.f, 0.f};
    f32x4 acc[4][2];
#pragma unroll
    for (int m = 0; m < 4; ++m) { acc[m][0] = z; acc[m][1] = z; }

    auto STAGE = [&](int buf, int kt) {
        char* base = smem + buf * 12288;
        int kb = kt * 64;
#pragma unroll
        for (int i = 0; i < 2; ++i) gload16(srcA[i] + kb, base + dA[i]);
        gload16(srcB + kb, base + dB);
    };

    STAGE(0, 0);
    __syncthreads();
#pragma unroll 4
    for (int t = 0; t < 16; ++t) {
        int cur = t & 1;
        if (t < 15) STAGE(cur ^ 1, t + 1);
        char* Ab = smem + cur * 12288;
        char* Bb = Ab + 8192;
        bf16x8 af[4], bg_[2];
#pragma unroll
        for (int m = 0; m < 4; ++m) {
            int row = wr * 64 + m * 16 + lr;
            af[m] = *(const bf16x8*)(Ab + row * 64 + SWZ(row, lg));
        }
#pragma unroll
        for (int n = 0; n < 2; ++n) {
            int row = wc * 32 + n * 16 + lr;
            bg_[n] = *(const bf16x8*)(Bb + row * 64 + SWZ(row, lg));
        }
#pragma unroll
        for (int m = 0; m < 4; ++m)
#pragma unroll
            for (int n = 0; n < 2; ++n)
                acc[m][n] = MFMA(af[m], bg_[n], acc[m][n], 0, 0, 0);
        __syncthreads();
    }

#pragma unroll
    for (int n = 0; n < 2; ++n) {
        int o = o0 + wc * 32 + n * 16 + lr;
        float bs = bo[o];
#pragma unroll
        for (int m = 0; m < 4; ++m) {
            int row = r0 + wr * 64 + m * 16 + lg * 4;
            int b = row >> 12, nn = row & (N_ - 1);
            size_t base = ((size_t)b * C_ + o) * N_ + nn;
            float4 xv = *(const float4*)(x + base);
            float4 ov;
            ov.x = acc[m][n][0] + bs + xv.x;
            ov.y = acc[m][n][1] + bs + xv.y;
            ov.z = acc[m][n][2] + bs + xv.z;
            ov.w = acc[m][n][3] + bs + xv.w;
            *(float4*)(out + base) = ov;
        }
    }
}

extern "C" void kernel_launch(void* const* d_in, const int* in_sizes, int n_in,
                              void* d_out, int out_size, void* d_ws, size_t ws_size,
                              hipStream_t stream) {
    const float* x  = (const float*)d_in[0];
    const float* Wq = (const float*)d_in[1];
    const float* bq = (const float*)d_in[2];
    const float* Wk = (const float*)d_in[3];
    const float* bk = (const float*)d_in[4];
    const float* Wv = (const float*)d_in[5];
    const float* bv = (const float*)d_in[6];
    const float* Wo = (const float*)d_in[7];
    const float* bo = (const float*)d_in[8];

    char* ws = (char*)d_ws;
    bf16* Q   = (bf16*)(ws + OFF_Q);
    bf16* K   = (bf16*)(ws + OFF_K);
    bf16* Vt  = (bf16*)(ws + OFF_VT);
    bf16* XT  = (bf16*)(ws + OFF_XT);
    bf16* WB  = (bf16*)(ws + OFF_WB);
    bf16* Op  = (bf16*)(ws + OFF_OP);
    float* ML = (float*)(ws + OFF_ML);
    float* out = (float*)d_out;

    hipLaunchKernelGGL(wcvt_kernel, dim3(256, 4), dim3(256), 0, stream, Wq, Wk, Wv, Wo, WB);
    hipLaunchKernelGGL(xt_kernel, dim3(64, 8, 2), dim3(256), 0, stream, x, XT);
    hipLaunchKernelGGL(qkv_kernel, dim3(64, 4, 3), dim3(256), 0, stream,
                       XT, WB, bq, bk, bv, Q, K, Vt);
    if (ws_size >= (size_t)WS_NEED_SPLIT) {
        hipLaunchKernelGGL(attn_kernel<2>, dim3(512), dim3(256), 0, stream,
                           Q, K, Vt, XT, Op, ML);
        hipLaunchKernelGGL(merge_kernel, dim3(2048), dim3(256), 0, stream, Op, ML, XT);
    } else {
        hipLaunchKernelGGL(attn_kernel<1>, dim3(256), dim3(256), 0, stream,
                           Q, K, Vt, XT, Op, ML);
    }
    hipLaunchKernelGGL(oproj_kernel, dim3(64, 8), dim3(256), 0, stream, XT, WB, bo, x, out);
}

// Round 13
// 132.082 us; speedup vs baseline: 2.2727x; 1.0427x over previous
//
#include <hip/hip_runtime.h>
#include <hip/hip_bf16.h>
#include <stdint.h>

#define B_ 2
#define C_ 512
#define G_ 4
#define D_ 128
#define N_ 4096

typedef __bf16 bf16;
typedef __bf16 bf16x8 __attribute__((ext_vector_type(8)));
typedef float  f32x4  __attribute__((ext_vector_type(4)));
typedef float  f32x16 __attribute__((ext_vector_type(16)));

#define MFMA   __builtin_amdgcn_mfma_f32_16x16x32_bf16
#define MFMA32 __builtin_amdgcn_mfma_f32_32x32x16_bf16

// LDS chunk swizzle for GEMMs: physical chunk = logical chunk ^ ((row>>1)&3)
#define SWZ(row, c) ((((c) ^ (((row) >> 1) & 3)) << 4))

// ---- workspace layout (bytes) ----
#define OFF_Q   (0u)           // [B*G][N][D] bf16 (pre-scaled by SC*log2e)
#define OFF_K   (8388608u)     // [B*G][N][D] bf16
#define OFF_VT  (16777216u)    // [B*G][D][N] bf16
#define OFF_XT  (25165824u)    // [B*N][C] bf16 (xT input; later attn O)
#define OFF_WB  (33554432u)    // 4 x [512][512] bf16
#define OFF_OP  (35651584u)    // bf16 [2][8][4096][128] partial O
#define OFF_ML  (52428800u)    // float2 [2][8][4096] running (m,l)
#define WS_NEED_SPLIT (52953088u)

__device__ inline unsigned pk2(float a, float b) {
    union { bf16 h[2]; unsigned u; } t;
    t.h[0] = (bf16)a; t.h[1] = (bf16)b;
    return t.u;
}
__device__ inline void pl32(unsigned &a, unsigned &b) {
    asm volatile("v_permlane32_swap_b32 %0, %1" : "+v"(a), "+v"(b));
}
__device__ inline void gload16(const char* src, char* lds) {
    __builtin_amdgcn_global_load_lds(
        (const __attribute__((address_space(1))) unsigned*)src,
        (__attribute__((address_space(3))) unsigned*)lds, 16, 0, 0);
}
__device__ inline float max3f(float a, float b, float c) {
    return fmaxf(fmaxf(a, b), c);   // clang fuses to v_max3_f32
}

// ---------- kernel 1: weights fp32 -> bf16 ----------
__global__ __launch_bounds__(256) void wcvt_kernel(const float* __restrict__ Wq,
                                                   const float* __restrict__ Wk,
                                                   const float* __restrict__ Wv,
                                                   const float* __restrict__ Wo,
                                                   bf16* __restrict__ out) {
    int m = blockIdx.y;
    const float* W = (m == 0) ? Wq : (m == 1) ? Wk : (m == 2) ? Wv : Wo;
    int i = (blockIdx.x * 256 + threadIdx.x) * 4;
    float4 v = *(const float4*)(W + i);
    union { bf16 h[4]; uint2 u; } pk;
    pk.h[0] = (bf16)v.x; pk.h[1] = (bf16)v.y; pk.h[2] = (bf16)v.z; pk.h[3] = (bf16)v.w;
    *(uint2*)(out + (size_t)m * (C_ * C_) + i) = pk.u;
}

// ---------- kernel 2: x [b][c][n] f32 -> xT [b*n][c] bf16 ----------
__global__ __launch_bounds__(256) void xt_kernel(const float* __restrict__ x,
                                                 bf16* __restrict__ xT) {
    __shared__ bf16 t[64 * 80];
    int n0 = blockIdx.x * 64, c0 = blockIdx.y * 64, b = blockIdx.z;
    const float* xp = x + (size_t)b * C_ * N_;
#pragma unroll
    for (int i = 0; i < 16; ++i) {
        int idx = threadIdx.x + 256 * i;
        int cl = idx >> 6, nl = idx & 63;
        float v = xp[(size_t)(c0 + cl) * N_ + n0 + nl];
        t[nl * 80 + cl] = (bf16)v;
    }
    __syncthreads();
    bf16* xt = xT + ((size_t)b * N_ + n0) * C_ + c0;
#pragma unroll
    for (int i = 0; i < 2; ++i) {
        int id = threadIdx.x + 256 * i;
        int nl = id >> 3, c8 = (id & 7) * 8;
        *(uint4*)(xt + (size_t)nl * C_ + c8) = *(const uint4*)(t + nl * 80 + c8);
    }
}

// ---------- kernel 3: fused QKV projection, 128x128 tile ----------
__global__ __launch_bounds__(256) void qkv_kernel(const bf16* __restrict__ xT,
                                                  const bf16* __restrict__ WB,
                                                  const float* __restrict__ bq,
                                                  const float* __restrict__ bk,
                                                  const float* __restrict__ bv,
                                                  bf16* __restrict__ Q,
                                                  bf16* __restrict__ K,
                                                  bf16* __restrict__ Vt) {
    __shared__ char smem[32768];
    const int tid = threadIdx.x;
    const int w = tid >> 6, l = tid & 63;
    const int lr = l & 15, lg = l >> 4;
    const int wr = w >> 1, wc = w & 1;
    const int mat = blockIdx.z;
    const bf16* A = xT;
    const bf16* W = WB + (size_t)mat * (C_ * C_);
    const float* bias = (mat == 0) ? bq : (mat == 1) ? bk : bv;
    const int r0 = blockIdx.x * 128, o0 = blockIdx.y * 128;
    const float QSCALE = 0.08838834764831845f * 1.4426950408889634f;

    const char* srcA[2]; const char* srcB[2]; int dA[2], dB[2];
#pragma unroll
    for (int i = 0; i < 2; ++i) {
        int CL = tid + 256 * i, row = CL >> 2, c = CL & 3;
        srcA[i] = (const char*)(A + (size_t)(r0 + row) * C_) + SWZ(row, c);
        srcB[i] = (const char*)(W + (size_t)(o0 + row) * C_) + SWZ(row, c);
        dA[i] = CL << 4;
        dB[i] = 8192 + (CL << 4);
    }

    f32x4 z = {0.f, 0.f, 0.f, 0.f};
    f32x4 acc[4][4];
#pragma unroll
    for (int m = 0; m < 4; ++m)
#pragma unroll
        for (int n = 0; n < 4; ++n) acc[m][n] = z;

    auto STAGE = [&](int buf, int kt) {
        char* base = smem + buf * 16384;
        int kb = kt * 64;
#pragma unroll
        for (int i = 0; i < 2; ++i) {
            gload16(srcA[i] + kb, base + dA[i]);
            gload16(srcB[i] + kb, base + dB[i]);
        }
    };

    STAGE(0, 0);
    __syncthreads();
#pragma unroll 4
    for (int t = 0; t < 16; ++t) {
        int cur = t & 1;
        if (t < 15) STAGE(cur ^ 1, t + 1);
        char* Ab = smem + cur * 16384;
        char* Bb = Ab + 8192;
        bf16x8 af[4], bg_[4];
#pragma unroll
        for (int m = 0; m < 4; ++m) {
            int row = wr * 64 + m * 16 + lr;
            af[m] = *(const bf16x8*)(Ab + row * 64 + SWZ(row, lg));
        }
#pragma unroll
        for (int n = 0; n < 4; ++n) {
            int row = wc * 64 + n * 16 + lr;
            bg_[n] = *(const bf16x8*)(Bb + row * 64 + SWZ(row, lg));
        }
#pragma unroll
        for (int m = 0; m < 4; ++m)
#pragma unroll
            for (int n = 0; n < 4; ++n)
                acc[m][n] = MFMA(af[m], bg_[n], acc[m][n], 0, 0, 0);
        __syncthreads();
    }

#pragma unroll
    for (int n = 0; n < 4; ++n) {
        int o = o0 + wc * 64 + n * 16 + lr;
        float bs = bias[o];
        int g = o >> 7, d = o & 127;
#pragma unroll
        for (int m = 0; m < 4; ++m) {
            int row = r0 + wr * 64 + m * 16 + lg * 4;
            int b = row >> 12, nn = row & (N_ - 1);
            if (mat == 0) {
#pragma unroll
                for (int j = 0; j < 4; ++j)
                    Q[((size_t)(b * G_ + g) * N_ + nn + j) * D_ + d] =
                        (bf16)((acc[m][n][j] + bs) * QSCALE);
            } else if (mat == 1) {
#pragma unroll
                for (int j = 0; j < 4; ++j)
                    K[((size_t)(b * G_ + g) * N_ + nn + j) * D_ + d] =
                        (bf16)(acc[m][n][j] + bs);
            } else {
                union { bf16 h[4]; uint2 u; } pk;
#pragma unroll
                for (int j = 0; j < 4; ++j) pk.h[j] = (bf16)(acc[m][n][j] + bs);
                *(uint2*)(Vt + ((size_t)(b * G_ + g) * D_ + d) * N_ + nn) = pk.u;
            }
        }
    }
}

// ---------- kernel 4: flash attention, 32x32 swapped-QK, KVB=64, 8-wave blocks ----------
// 8 waves x 32 q = 256 q/block, grid 256 -> 1 block/CU: per-CU KV staging bytes
// HALVE vs 2x 4-wave blocks (the round-12 bottleneck model). LDS 64KB, VGPR free
// to ~256 (launch_bounds(512,2) -- NOT ,4 which forced 64 VGPR + spills in r11).
template<int SPLITS>
__global__ __launch_bounds__(512, 2) void attn_kernel(const bf16* __restrict__ Q,
                                                      const bf16* __restrict__ K,
                                                      const bf16* __restrict__ Vt,
                                                      bf16* __restrict__ XT,
                                                      bf16* __restrict__ Op,
                                                      float* __restrict__ ML) {
    __shared__ char smem[65536];
    const int tid = threadIdx.x;
    const int w = tid >> 6, l = tid & 63;
    const int l31 = l & 31, h = l >> 5;

    // 1-D grid: 256 (SPLITS=2) or 128 (SPLITS=1); xcd = L%8 -> head
    const int L = blockIdx.x;
    const int bg = L & 7;
    const int ix = L >> 3;
    const int sp = (SPLITS > 1) ? (ix >> 4) : 0;
    const int qb = (SPLITS > 1) ? (ix & 15) : ix;

    const bf16* Qh = Q + (size_t)bg * N_ * D_;
    const char* Kh = (const char*)(K + (size_t)bg * N_ * D_);
    const char* Vh = (const char*)(Vt + (size_t)bg * D_ * N_);
    const int q0 = qb * 256 + w * 32;
    const int kv0 = sp * (N_ / SPLITS);
    const int NT = N_ / SPLITS / 64;

    // staging offsets: 8 waves x 2 chunks each for K (16 x 1KB) and V
    int offK[2], offV[2];
#pragma unroll
    for (int j = 0; j < 2; ++j) {
        int CL = (w * 2 + j) * 64 + l;
        int row = CL >> 4;
        int cp = (CL & 15) ^ (row & 15);
        offK[j] = row * 256 + cp * 16;
        int dv = 2 * row + (cp >> 3), k8 = cp & 7;
        offV[j] = dv * (N_ * 2) + k8 * 16;
    }

    bf16x8 aq[8];
#pragma unroll
    for (int kb = 0; kb < 8; ++kb)
        aq[kb] = *(const bf16x8*)(Qh + (size_t)(q0 + l31) * D_ + kb * 16 + h * 8);

    bf16 one_ = (bf16)1.0f;
    bf16x8 ones = {one_, one_, one_, one_, one_, one_, one_, one_};

    f32x16 oacc[4], lacc;
#pragma unroll
    for (int dt = 0; dt < 4; ++dt)
#pragma unroll
        for (int r = 0; r < 16; ++r) oacc[dt][r] = 0.f;
#pragma unroll
    for (int r = 0; r < 16; ++r) lacc[r] = 0.f;
    float mrun = -1e30f;
    const float THR = 5.0f;

    auto STAGE = [&](int buf, int kv) {
        const char* pk = Kh + (size_t)kv * 256;
        const char* pv = Vh + (size_t)kv * 2;
        char* kb = smem + buf * 32768 + w * 2048;
        char* vb = smem + buf * 32768 + 16384 + w * 2048;
#pragma unroll
        for (int j = 0; j < 2; ++j) gload16(pk + offK[j], kb + j * 1024);
#pragma unroll
        for (int j = 0; j < 2; ++j) gload16(pv + offV[j], vb + j * 1024);
    };

    STAGE(0, kv0);

    for (int t = 0; t < NT; ++t) {
        int cur = t & 1;
        __builtin_amdgcn_s_barrier();
        if (t + 1 < NT) {
            STAGE(cur ^ 1, kv0 + (t + 1) * 64);
            asm volatile("s_waitcnt vmcnt(4)" ::: "memory");  // drain tile t, keep t+1
        } else {
            asm volatile("s_waitcnt vmcnt(0)" ::: "memory");
        }
        __builtin_amdgcn_sched_barrier(0);
        __builtin_amdgcn_s_barrier();
        char* Kb = smem + cur * 32768;
        char* Vb = smem + cur * 32768 + 16384;

        // ---- S^T = K Q^T ----
        f32x16 s0, s1;
#pragma unroll
        for (int r = 0; r < 16; ++r) { s0[r] = 0.f; s1[r] = 0.f; }
        __builtin_amdgcn_s_setprio(1);
#pragma unroll
        for (int kb = 0; kb < 8; ++kb) {
            int ch = (((kb << 1) | h) ^ (l31 & 15)) << 4;
            bf16x8 kf0 = *(const bf16x8*)(Kb + (size_t)l31 * 256 + ch);
            s0 = MFMA32(kf0, aq[kb], s0, 0, 0, 0);
            bf16x8 kf1 = *(const bf16x8*)(Kb + (size_t)(32 + l31) * 256 + ch);
            s1 = MFMA32(kf1, aq[kb], s1, 0, 0, 0);
        }
        __builtin_amdgcn_s_setprio(0);

        // ---- tile max via max3 tree (lane owns q = l31) ----
        float x0 = max3f(s0[0],  s0[1],  s0[2]);
        float x1 = max3f(s0[3],  s0[4],  s0[5]);
        float x2 = max3f(s0[6],  s0[7],  s0[8]);
        float x3 = max3f(s0[9],  s0[10], s0[11]);
        float x4 = max3f(s0[12], s0[13], s0[14]);
        float x5 = max3f(s0[15], s1[0],  s1[1]);
        float x6 = max3f(s1[2],  s1[3],  s1[4]);
        float x7 = max3f(s1[5],  s1[6],  s1[7]);
        float x8 = max3f(s1[8],  s1[9],  s1[10]);
        float x9 = max3f(s1[11], s1[12], s1[13]);
        float xa = fmaxf(s1[14], s1[15]);
        float y0 = max3f(x0, x1, x2);
        float y1 = max3f(x3, x4, x5);
        float y2 = max3f(x6, x7, x8);
        float y3 = fmaxf(x9, xa);
        float mt = fmaxf(max3f(y0, y1, y2), y3);
        mt = fmaxf(mt, __shfl_xor(mt, 32));

        if (__any(mt > mrun + THR)) {
            float mn = fmaxf(mrun, mt);
            float corr = __builtin_amdgcn_exp2f(mrun - mn);
            mrun = mn;
#pragma unroll
            for (int r = 0; r < 16; ++r) {
                int qr = (r & 3) + 8 * (r >> 2) + 4 * h;
                float cr = __shfl(corr, qr);
                lacc[r] *= cr;
#pragma unroll
                for (int dt = 0; dt < 4; ++dt) oacc[dt][r] *= cr;
            }
        }

#pragma unroll
        for (int r = 0; r < 16; ++r) {
            s0[r] = __builtin_amdgcn_exp2f(s0[r] - mrun);
            s1[r] = __builtin_amdgcn_exp2f(s1[r] - mrun);
        }

        // ---- P -> bf16 PV A-fragments via pack + permlane32_swap ----
        bf16x8 pa0, pa1, pa2, pa3;
        {
            unsigned x0_ = pk2(s0[0], s0[1]),  y0_ = pk2(s0[4], s0[5]);  pl32(x0_, y0_);
            unsigned x1_ = pk2(s0[2], s0[3]),  y1_ = pk2(s0[6], s0[7]);  pl32(x1_, y1_);
            pa0 = __builtin_bit_cast(bf16x8, (uint4){x0_, x1_, y0_, y1_});
            unsigned x2_ = pk2(s0[8], s0[9]),  y2_ = pk2(s0[12], s0[13]); pl32(x2_, y2_);
            unsigned x3_ = pk2(s0[10], s0[11]), y3_ = pk2(s0[14], s0[15]); pl32(x3_, y3_);
            pa1 = __builtin_bit_cast(bf16x8, (uint4){x2_, x3_, y2_, y3_});
            unsigned x4_ = pk2(s1[0], s1[1]),  y4_ = pk2(s1[4], s1[5]);  pl32(x4_, y4_);
            unsigned x5_ = pk2(s1[2], s1[3]),  y5_ = pk2(s1[6], s1[7]);  pl32(x5_, y5_);
            pa2 = __builtin_bit_cast(bf16x8, (uint4){x4_, x5_, y4_, y5_});
            unsigned x6_ = pk2(s1[8], s1[9]),  y6_ = pk2(s1[12], s1[13]); pl32(x6_, y6_);
            unsigned x7_ = pk2(s1[10], s1[11]), y7_ = pk2(s1[14], s1[15]); pl32(x7_, y7_);
            pa3 = __builtin_bit_cast(bf16x8, (uint4){x6_, x7_, y6_, y7_});
        }

        // ---- O += P V ; l += P 1 (row-sum on the MFMA pipe) ----
        __builtin_amdgcn_s_setprio(1);
#pragma unroll
        for (int sl = 0; sl < 4; ++sl) {
            bf16x8 pa = (sl == 0) ? pa0 : (sl == 1) ? pa1 : (sl == 2) ? pa2 : pa3;
#pragma unroll
            for (int dt = 0; dt < 4; ++dt) {
                int row = dt * 16 + (l31 >> 1);
                int ch = ((((l31 & 1) << 3) + (sl << 1) + h) ^ (l31 >> 1)) << 4;
                bf16x8 vf = *(const bf16x8*)(Vb + (size_t)row * 256 + ch);
                oacc[dt] = MFMA32(pa, vf, oacc[dt], 0, 0, 0);
            }
            lacc = MFMA32(pa, ones, lacc, 0, 0, 0);
        }
        __builtin_amdgcn_s_setprio(0);
    }

    // ---- epilogue ----
    if (SPLITS > 1) {
        float2* mlp = (float2*)ML + ((size_t)sp * 8 + bg) * N_ + q0;
#pragma unroll
        for (int r = 0; r < 16; ++r) {
            int qr = (r & 3) + 8 * (r >> 2) + 4 * h;
            float mv = __shfl(mrun, qr);
            if (l31 == 0) {
                float2 v; v.x = mv; v.y = lacc[r];
                mlp[qr] = v;
            }
        }
        bf16* op = Op + (((size_t)sp * 8 + bg) * N_ + q0) * D_;
#pragma unroll
        for (int dt = 0; dt < 4; ++dt)
#pragma unroll
            for (int r = 0; r < 16; ++r) {
                int qr = (r & 3) + 8 * (r >> 2) + 4 * h;
                op[(size_t)qr * D_ + dt * 32 + l31] = (bf16)oacc[dt][r];
            }
    } else {
        int b = bg >> 2, g = bg & 3;
#pragma unroll
        for (int r = 0; r < 16; ++r) {
            int qr = (r & 3) + 8 * (r >> 2) + 4 * h;
            float iv = 1.f / lacc[r];
#pragma unroll
            for (int dt = 0; dt < 4; ++dt)
                XT[((size_t)b * N_ + q0 + qr) * C_ + g * D_ + dt * 32 + l31] =
                    (bf16)(oacc[dt][r] * iv);
        }
    }
}

// ---------- kernel 4b: merge the 2 KV-split partials ----------
__global__ __launch_bounds__(256) void merge_kernel(const bf16* __restrict__ Op,
                                                    const float* __restrict__ ML,
                                                    bf16* __restrict__ XT) {
    int t = threadIdx.x & 15, rl = threadIdx.x >> 4;
    int r = blockIdx.x * 16 + rl;
    int bg = r >> 12, n = r & (N_ - 1);
    const float2* mlp = (const float2*)ML;
    float2 ml0 = mlp[r], ml1 = mlp[32768 + r];
    float mm = fmaxf(ml0.x, ml1.x);
    float w0 = __builtin_amdgcn_exp2f(ml0.x - mm);
    float w1 = __builtin_amdgcn_exp2f(ml1.x - mm);
    float inv = 1.f / (w0 * ml0.y + w1 * ml1.y);
    w0 *= inv; w1 *= inv;
    bf16x8 o0 = *(const bf16x8*)(Op + (size_t)r * D_ + t * 8);
    bf16x8 o1 = *(const bf16x8*)(Op + (size_t)(32768 + r) * D_ + t * 8);
    union { bf16 h[8]; uint4 u; } pk;
#pragma unroll
    for (int e = 0; e < 8; ++e)
        pk.h[e] = (bf16)(w0 * (float)o0[e] + w1 * (float)o1[e]);
    int b = bg >> 2, g = bg & 3;
    *(uint4*)(XT + ((size_t)b * N_ + n) * C_ + g * D_ + t * 8) = pk.u;
}

// ---------- kernel 5: output projection, 128x64 tile ----------
__global__ __launch_bounds__(256) void oproj_kernel(const bf16* __restrict__ Ob,
                                                    const bf16* __restrict__ WB,
                                                    const float* __restrict__ bo,
                                                    const float* __restrict__ x,
                                                    float* __restrict__ out) {
    __shared__ char smem[24576];
    const int tid = threadIdx.x;
    const int w = tid >> 6, l = tid & 63;
    const int lr = l & 15, lg = l >> 4;
    const int wr = w >> 1, wc = w & 1;
    const bf16* W = WB + (size_t)3 * (C_ * C_);
    const int r0 = blockIdx.x * 128, o0 = blockIdx.y * 64;

    const char* srcA[2]; int dA[2];
#pragma unroll
    for (int i = 0; i < 2; ++i) {
        int CL = tid + 256 * i, row = CL >> 2, c = CL & 3;
        srcA[i] = (const char*)(Ob + (size_t)(r0 + row) * C_) + SWZ(row, c);
        dA[i] = CL << 4;
    }
    const char* srcB; int dB;
    {
        int CL = tid, row = CL >> 2, c = CL & 3;
        srcB = (const char*)(W + (size_t)(o0 + row) * C_) + SWZ(row, c);
        dB = 8192 + (CL << 4);
    }

    f32x4 z = {0.f, 0.f, 0.f, 0.f};
    f32x4 acc[4][2];
#pragma unroll
    for (int m = 0; m < 4; ++m) { acc[m][0] = z; acc[m][1] = z; }

    auto STAGE = [&](int buf, int kt) {
        char* base = smem + buf * 12288;
        int kb = kt * 64;
#pragma unroll
        for (int i = 0; i < 2; ++i) gload16(srcA[i] + kb, base + dA[i]);
        gload16(srcB + kb, base + dB);
    };

    STAGE(0, 0);
    __syncthreads();
#pragma unroll 4
    for (int t = 0; t < 16; ++t) {
        int cur = t & 1;
        if (t < 15) STAGE(cur ^ 1, t + 1);
        char* Ab = smem + cur * 12288;
        char* Bb = Ab + 8192;
        bf16x8 af[4], bg_[2];
#pragma unroll
        for (int m = 0; m < 4; ++m) {
            int row = wr * 64 + m * 16 + lr;
            af[m] = *(const bf16x8*)(Ab + row * 64 + SWZ(row, lg));
        }
#pragma unroll
        for (int n = 0; n < 2; ++n) {
            int row = wc * 32 + n * 16 + lr;
            bg_[n] = *(const bf16x8*)(Bb + row * 64 + SWZ(row, lg));
        }
#pragma unroll
        for (int m = 0; m < 4; ++m)
#pragma unroll
            for (int n = 0; n < 2; ++n)
                acc[m][n] = MFMA(af[m], bg_[n], acc[m][n], 0, 0, 0);
        __syncthreads();
    }

#pragma unroll
    for (int n = 0; n < 2; ++n) {
        int o = o0 + wc * 32 + n * 16 + lr;
        float bs = bo[o];
#pragma unroll
        for (int m = 0; m < 4; ++m) {
            int row = r0 + wr * 64 + m * 16 + lg * 4;
            int b = row >> 12, nn = row & (N_ - 1);
            size_t base = ((size_t)b * C_ + o) * N_ + nn;
            float4 xv = *(const float4*)(x + base);
            float4 ov;
            ov.x = acc[m][n][0] + bs + xv.x;
            ov.y = acc[m][n][1] + bs + xv.y;
            ov.z = acc[m][n][2] + bs + xv.z;
            ov.w = acc[m][n][3] + bs + xv.w;
            *(float4*)(out + base) = ov;
        }
    }
}

extern "C" void kernel_launch(void* const* d_in, const int* in_sizes, int n_in,
                              void* d_out, int out_size, void* d_ws, size_t ws_size,
                              hipStream_t stream) {
    const float* x  = (const float*)d_in[0];
    const float* Wq = (const float*)d_in[1];
    const float* bq = (const float*)d_in[2];
    const float* Wk = (const float*)d_in[3];
    const float* bk = (const float*)d_in[4];
    const float* Wv = (const float*)d_in[5];
    const float* bv = (const float*)d_in[6];
    const float* Wo = (const float*)d_in[7];
    const float* bo = (const float*)d_in[8];

    char* ws = (char*)d_ws;
    bf16* Q   = (bf16*)(ws + OFF_Q);
    bf16* K   = (bf16*)(ws + OFF_K);
    bf16* Vt  = (bf16*)(ws + OFF_VT);
    bf16* XT  = (bf16*)(ws + OFF_XT);
    bf16* WB  = (bf16*)(ws + OFF_WB);
    bf16* Op  = (bf16*)(ws + OFF_OP);
    float* ML = (float*)(ws + OFF_ML);
    float* out = (float*)d_out;

    hipLaunchKernelGGL(wcvt_kernel, dim3(256, 4), dim3(256), 0, stream, Wq, Wk, Wv, Wo, WB);
    hipLaunchKernelGGL(xt_kernel, dim3(64, 8, 2), dim3(256), 0, stream, x, XT);
    hipLaunchKernelGGL(qkv_kernel, dim3(64, 4, 3), dim3(256), 0, stream,
                       XT, WB, bq, bk, bv, Q, K, Vt);
    if (ws_size >= (size_t)WS_NEED_SPLIT) {
        hipLaunchKernelGGL(attn_kernel<2>, dim3(256), dim3(512), 0, stream,
                           Q, K, Vt, XT, Op, ML);
        hipLaunchKernelGGL(merge_kernel, dim3(2048), dim3(256), 0, stream, Op, ML, XT);
    } else {
        hipLaunchKernelGGL(attn_kernel<1>, dim3(128), dim3(512), 0, stream,
                           Q, K, Vt, XT, Op, ML);
    }
    hipLaunchKernelGGL(oproj_kernel, dim3(64, 8), dim3(256), 0, stream, XT, WB, bo, x, out);
}